// Round 17
// baseline (112.276 us; speedup 1.0000x reference)
//
#include <hip/hip_runtime.h>

// CapsNet forward.
// packAll: w2 -> MFMA B-fragments + W_route -> f16 c-pairs
// conv_fused: conv1 (fp32) -> sOut LDS [400][20-pad f16] -> conv2 MFMA
//             (waves 0-1, B-frags from global L2) -> u [B][144][8]  (R16 proven)
// routing2: R16 structure + ILP restructure: batched LDS loads + split
//           accumulators in spart / b-update / softmax (break latency chains).

typedef _Float16 half2_t __attribute__((ext_vector_type(2)));
typedef _Float16 f16x4 __attribute__((ext_vector_type(4)));
typedef _Float16 f16x8 __attribute__((ext_vector_type(8)));
typedef float f32x16 __attribute__((ext_vector_type(16)));

static __device__ __forceinline__ float fdot2f(half2_t a, half2_t b, float c) {
#if __has_builtin(__builtin_amdgcn_fdot2)
  return __builtin_amdgcn_fdot2(a, b, c, false);
#else
  return c + (float)a[0] * (float)b[0] + (float)a[1] * (float)b[1];
#endif
}

static __device__ __forceinline__ half2_t h2(unsigned int u) {
  return __builtin_bit_cast(half2_t, u);
}

static __device__ __forceinline__ unsigned int pkh2(float a, float b) {
  half2_t h;
  h[0] = (_Float16)a;
  h[1] = (_Float16)b;
  return __builtin_bit_cast(unsigned int, h);
}

static __device__ __forceinline__ f32x16 zero16() {
  f32x16 z = {0.f, 0.f, 0.f, 0.f, 0.f, 0.f, 0.f, 0.f,
              0.f, 0.f, 0.f, 0.f, 0.f, 0.f, 0.f, 0.f};
  return z;
}

// Fused packs. idx < 92160: W_route -> wPr f16 c-pairs.
//              idx < 41472: w2 -> wBg MFMA B-fragments.
__global__ __launch_bounds__(256) void packAll(
    const float* __restrict__ w2, const float* __restrict__ Wr,
    _Float16* __restrict__ wBg, unsigned int* __restrict__ wPr) {
  int idx = blockIdx.x * 256 + threadIdx.x;
  if (idx < 92160) {
    int cp = idx & 3;
    int row = idx >> 2;
    const float* src = Wr + (size_t)row * 8 + cp * 2;
    wPr[idx] = pkh2(src[0], src[1]);
  }
  if (idx < 41472) {
    int j = idx & 7;
    int lane = (idx >> 3) & 63;
    int step = idx >> 9;
    int kh = step / 9, kw = step - kh * 9;
    int co = lane & 31, ci = (lane >> 5) * 8 + j;
    wBg[idx] = (_Float16)w2[(co * 16 + ci) * 81 + kh * 9 + kw];
  }
}

// conv_fused: block = 1 sample, 320 threads (5 waves). (R16 proven)
__global__ __launch_bounds__(320) void conv_fused(
    const float* __restrict__ in, const float* __restrict__ w,
    const float* __restrict__ bias1, const _Float16* __restrict__ wBg,
    const float* __restrict__ bias2, float* __restrict__ u) {
  __shared__ __align__(16) float sIn[784];      // 28x28
  __shared__ float sW[1296];                    // 16x81
  __shared__ __align__(16) _Float16 sOut[8000]; // [ih*20+iw][20] (16 used)
  int b = blockIdx.x, t = threadIdx.x;
  const float* inb = in + b * 784;
  for (int i = t; i < 784; i += 320) sIn[i] = inb[i];
  for (int i = t; i < 1296; i += 320) sW[i] = w[i];
  __syncthreads();
  {
    int co = t / 20, oh = t % 20;   // 16*20 = 320 work items
    float bv = bias1[co];
    float acc[20];
#pragma unroll
    for (int j = 0; j < 20; ++j) acc[j] = bv;
#pragma unroll
    for (int kh = 0; kh < 9; ++kh) {
      float r[28];
      const float4* row = (const float4*)&sIn[(oh + kh) * 28];
#pragma unroll
      for (int q = 0; q < 7; ++q) {
        float4 v = row[q];
        r[q * 4 + 0] = v.x; r[q * 4 + 1] = v.y; r[q * 4 + 2] = v.z; r[q * 4 + 3] = v.w;
      }
      const float* wr = &sW[co * 81 + kh * 9];
#pragma unroll
      for (int kw = 0; kw < 9; ++kw) {
        float wv = wr[kw];
#pragma unroll
        for (int j = 0; j < 20; ++j) acc[j] += wv * r[kw + j];
      }
    }
#pragma unroll
    for (int j = 0; j < 20; ++j) sOut[(oh * 20 + j) * 20 + co] = (_Float16)acc[j];
  }
  __syncthreads();

  // ---- conv2 MFMA: waves 0-1 (rows r = wv*32 + l31; valid r < 36) ----
  int wv = t >> 6, lane = t & 63;
  if (wv < 2) {
    int l31 = lane & 31, half = lane >> 5;
    int r = wv * 32 + l31;
    int rc = (r < 36) ? r : 35;
    int oh = rc / 6, ow = rc - oh * 6;
    int tb = (oh * 40 + ow * 2) * 20 + half * 8;
    f32x16 acc = zero16();
    for (int kh = 0; kh < 9; ++kh) {
      int abase = tb + kh * 400;   // (kh*20)*20
#pragma unroll
      for (int kw = 0; kw < 9; ++kw) {
        f16x8 bf = *(const f16x8*)(wBg + ((kh * 9 + kw) * 64 + lane) * 8);
        const _Float16* ap = sOut + abase + kw * 20;
        f16x4 lo = *(const f16x4*)ap;
        f16x4 hi = *(const f16x4*)(ap + 4);
        f16x8 a = __builtin_shufflevector(lo, hi, 0, 1, 2, 3, 4, 5, 6, 7);
        acc = __builtin_amdgcn_mfma_f32_32x32x16_f16(a, bf, acc, 0, 0, 0);
      }
    }
    float bv = bias2[l31];
    int c8 = l31 >> 2;
    int ibco = (l31 & 3) * 36;
    float* ub = u + (size_t)b * 1152;
#pragma unroll
    for (int reg = 0; reg < 16; ++reg) {
      int rr = wv * 32 + (reg & 3) + 8 * (reg >> 2) + 4 * half;
      if (rr < 36) ub[(ibco + rr) * 8 + c8] = acc[reg] + bv;
    }
  }
}

// routing2: block = 2 samples, 1024 threads. u_hat f16 in LDS (stride 82).
// ILP restructure: all phase loops batch LDS loads 4-8 wide with split accums.
__global__ __launch_bounds__(1024) void routing2_kernel(
    const float* __restrict__ u, const unsigned int* __restrict__ wPr,
    float* __restrict__ out, int B) {
  __shared__ unsigned int uhh[2][11808];   // [sl][i*82+dp] f16 d-pairs (80 used)
  __shared__ unsigned int ush[2][576];     // u f16 c-pairs [i][4]
  __shared__ float blog[2][1440];
  __shared__ float cc[2][1440];
  __shared__ float spart[2][960];          // [sl][ch 6][160]
  __shared__ float ss[2][160];
  __shared__ float vv[2][160];
  __shared__ unsigned int vvh[2][80];
  int b0 = blockIdx.x * 2, t = threadIdx.x;
  for (int j = t; j < 1152; j += 1024) {
    int sl2 = j / 576, k = j - sl2 * 576;
    float2 p = *(const float2*)(u + (size_t)(b0 + sl2) * 1152 + k * 2);
    ush[sl2][k] = pkh2(p.x, p.y);
  }
  for (int j = t; j < 2880; j += 1024) blog[j / 1440][j % 1440] = 0.f;
  __syncthreads();

  // ---- u_hat with 2-deep W prefetch ----
  {
    const uint4* W4 = (const uint4*)wPr;   // rows [i*160+o*16+d] of 8 f16
    int idx = t;
    bool valid = idx < 11520;
    int i_ = 0, dp_ = 0;
    uint4 w0a, w1a;
    if (valid) {
      i_ = idx / 80; dp_ = idx - i_ * 80;
      int row = i_ * 160 + (dp_ >> 3) * 16 + (dp_ & 7) * 2;
      w0a = W4[row]; w1a = W4[row + 1];
    }
    while (valid) {
      int nidx = idx + 1024;
      bool nvalid = nidx < 11520;
      int ni = 0, ndp = 0;
      uint4 w0b, w1b;
      if (nvalid) {
        ni = nidx / 80; ndp = nidx - ni * 80;
        int nrow = ni * 160 + (ndp >> 3) * 16 + (ndp & 7) * 2;
        w0b = W4[nrow]; w1b = W4[nrow + 1];
      }
#pragma unroll
      for (int sl2 = 0; sl2 < 2; ++sl2) {
        const uint2* up = (const uint2*)&ush[sl2][i_ * 4];
        uint2 ua = up[0], ub = up[1];
        half2_t u0 = h2(ua.x), u1 = h2(ua.y), u2 = h2(ub.x), u3 = h2(ub.y);
        float a0 = fdot2f(h2(w0a.x), u0,
                   fdot2f(h2(w0a.y), u1,
                   fdot2f(h2(w0a.z), u2, fdot2f(h2(w0a.w), u3, 0.f))));
        float a1 = fdot2f(h2(w1a.x), u0,
                   fdot2f(h2(w1a.y), u1,
                   fdot2f(h2(w1a.z), u2, fdot2f(h2(w1a.w), u3, 0.f))));
        uhh[sl2][i_ * 82 + dp_] = pkh2(a0, a1);
      }
      idx = nidx; i_ = ni; dp_ = ndp;
      w0a = w0b; w1a = w1b;
      valid = nvalid;
    }
  }
  __syncthreads();

  int sl = t >> 9, tl = t & 511;
  for (int it = 0; it < 3; ++it) {
    if (it > 0) {
      if (tl < 144) {
        const float* br = &blog[sl][tl * 10];
        // batched row read (5 x float2, independent)
        float2 p0 = *(const float2*)br;
        float2 p1 = *(const float2*)(br + 2);
        float2 p2 = *(const float2*)(br + 4);
        float2 p3 = *(const float2*)(br + 6);
        float2 p4 = *(const float2*)(br + 8);
        float e[10] = {p0.x, p0.y, p1.x, p1.y, p2.x,
                       p2.y, p3.x, p3.y, p4.x, p4.y};
        float m01 = fmaxf(e[0], e[1]), m23 = fmaxf(e[2], e[3]);
        float m45 = fmaxf(e[4], e[5]), m67 = fmaxf(e[6], e[7]);
        float m89 = fmaxf(e[8], e[9]);
        float mx = fmaxf(fmaxf(fmaxf(m01, m23), fmaxf(m45, m67)), m89);
        float sum = 0.f;
#pragma unroll
        for (int o = 0; o < 10; ++o) { e[o] = __expf(e[o] - mx); sum += e[o]; }
        float inv = 1.0f / sum;
        float* cr = &cc[sl][tl * 10];
#pragma unroll
        for (int q = 0; q < 5; ++q)
          *(float2*)(cr + 2 * q) = make_float2(e[2 * q] * inv, e[2 * q + 1] * inv);
      }
      __syncthreads();
    }
    // s partials: 480 lanes = 6 i-chunks x 80 d-pairs; 4-wide batched loads,
    // 4 split accumulators (break the ds_read latency chain).
    if (tl < 480) {
      int ch = tl / 80, dp = tl - ch * 80;
      int o = dp >> 3;
      int i0 = ch * 24;
      float a0 = 0.f, a1 = 0.f, a2 = 0.f, a3 = 0.f;
      if (it == 0) {
#pragma unroll
        for (int k = 0; k < 24; k += 4) {
          unsigned int r0 = uhh[sl][(i0 + k + 0) * 82 + dp];
          unsigned int r1 = uhh[sl][(i0 + k + 1) * 82 + dp];
          unsigned int r2 = uhh[sl][(i0 + k + 2) * 82 + dp];
          unsigned int r3 = uhh[sl][(i0 + k + 3) * 82 + dp];
          half2_t H0 = h2(r0), H1 = h2(r1), H2 = h2(r2), H3 = h2(r3);
          a0 += (float)H0[0]; a1 += (float)H0[1];
          a2 += (float)H1[0]; a3 += (float)H1[1];
          a0 += (float)H2[0]; a1 += (float)H2[1];
          a2 += (float)H3[0]; a3 += (float)H3[1];
        }
      } else {
#pragma unroll
        for (int k = 0; k < 24; k += 4) {
          unsigned int r0 = uhh[sl][(i0 + k + 0) * 82 + dp];
          unsigned int r1 = uhh[sl][(i0 + k + 1) * 82 + dp];
          unsigned int r2 = uhh[sl][(i0 + k + 2) * 82 + dp];
          unsigned int r3 = uhh[sl][(i0 + k + 3) * 82 + dp];
          float c0 = cc[sl][(i0 + k + 0) * 10 + o];
          float c1 = cc[sl][(i0 + k + 1) * 10 + o];
          float c2 = cc[sl][(i0 + k + 2) * 10 + o];
          float c3 = cc[sl][(i0 + k + 3) * 10 + o];
          half2_t H0 = h2(r0), H1 = h2(r1), H2 = h2(r2), H3 = h2(r3);
          a0 += c0 * (float)H0[0]; a1 += c0 * (float)H0[1];
          a2 += c1 * (float)H1[0]; a3 += c1 * (float)H1[1];
          a0 += c2 * (float)H2[0]; a1 += c2 * (float)H2[1];
          a2 += c3 * (float)H3[0]; a3 += c3 * (float)H3[1];
        }
      }
      spart[sl][ch * 160 + dp * 2] = a0 + a2;
      spart[sl][ch * 160 + dp * 2 + 1] = a1 + a3;
    }
    __syncthreads();
    if (tl < 160) {
      float s0 = spart[sl][tl], s1 = spart[sl][160 + tl];
      float s2 = spart[sl][320 + tl], s3 = spart[sl][480 + tl];
      float s4 = spart[sl][640 + tl], s5 = spart[sl][800 + tl];
      float s = (s0 + s1) + (s2 + s3) + (s4 + s5);
      ss[sl][tl] = (it == 0) ? s * 0.1f : s;   // it==0: softmax of zeros = 0.1
    }
    __syncthreads();
    if (tl < 10) {
      const float* sr = &ss[sl][tl * 16];
      float4 q0 = *(const float4*)sr;
      float4 q1 = *(const float4*)(sr + 4);
      float4 q2 = *(const float4*)(sr + 8);
      float4 q3 = *(const float4*)(sr + 12);
      float sq = q0.x * q0.x + q0.y * q0.y + q0.z * q0.z + q0.w * q0.w +
                 q1.x * q1.x + q1.y * q1.y + q1.z * q1.z + q1.w * q1.w +
                 q2.x * q2.x + q2.y * q2.y + q2.z * q2.z + q2.w * q2.w +
                 q3.x * q3.x + q3.y * q3.y + q3.z * q3.z + q3.w * q3.w;
      float coef = (sq / (1.0f + sq)) / sqrtf(sq + 1e-8f);
#pragma unroll
      for (int q = 0; q < 8; ++q) {
        float v0 = coef * sr[2 * q];
        float v1 = coef * sr[2 * q + 1];
        vv[sl][tl * 16 + 2 * q] = v0;
        vv[sl][tl * 16 + 2 * q + 1] = v1;
        vvh[sl][tl * 8 + q] = pkh2(v0, v1);
      }
      if (it == 2) out[(b0 + sl) * 10 + tl] = coef * sqrtf(sq);   // pred
    }
    __syncthreads();
    if (it < 2) {
      for (int idx = t; idx < 2880; idx += 1024) {
        int s2 = idx / 1440, r = idx - s2 * 1440;
        int i = r / 10, o = r - i * 10;
        const uint2* uhp = (const uint2*)&uhh[s2][i * 82 + o * 8];
        const uint2* vp = (const uint2*)&vvh[s2][o * 8];
        // batch all loads, then two parallel fdot2 chains
        uint2 A0 = uhp[0], A1 = uhp[1], A2 = uhp[2], A3 = uhp[3];
        uint2 V0 = vp[0], V1 = vp[1], V2 = vp[2], V3 = vp[3];
        float da = fdot2f(h2(A0.x), h2(V0.x), fdot2f(h2(A0.y), h2(V0.y), 0.f));
        float db = fdot2f(h2(A1.x), h2(V1.x), fdot2f(h2(A1.y), h2(V1.y), 0.f));
        da = fdot2f(h2(A2.x), h2(V2.x), fdot2f(h2(A2.y), h2(V2.y), da));
        db = fdot2f(h2(A3.x), h2(V3.x), fdot2f(h2(A3.y), h2(V3.y), db));
        blog[s2][r] += da + db;
      }
      __syncthreads();
    }
  }
  if (tl < 160) out[B * 10 + (b0 + sl) * 160 + tl] = vv[sl][tl];
}

extern "C" void kernel_launch(void* const* d_in, const int* in_sizes, int n_in,
                              void* d_out, int out_size, void* d_ws, size_t ws_size,
                              hipStream_t stream) {
  const float* in = (const float*)d_in[0];
  const float* w1 = (const float*)d_in[1];
  const float* b1 = (const float*)d_in[2];
  const float* w2 = (const float*)d_in[3];
  const float* b2 = (const float*)d_in[4];
  const float* Wr = (const float*)d_in[5];
  float* out = (float*)d_out;
  int B = in_sizes[0] / 784;
  float* wsf = (float*)d_ws;

  float* u = wsf;                                    // [B][1152] f32
  float* tail = wsf + (size_t)B * 1152;
  _Float16* wBg = (_Float16*)tail;                   // 41472 f16 = 20736 f
  unsigned int* wPr = (unsigned int*)(tail + 20736); // 92160 dw

  packAll<<<360, 256, 0, stream>>>(w2, Wr, wBg, wPr);
  conv_fused<<<B, 320, 0, stream>>>(in, w1, b1, wBg, b2, u);
  routing2_kernel<<<B / 2, 1024, 0, stream>>>(u, wPr, out, B);
}